// Round 1
// baseline (382.204 us; speedup 1.0000x reference)
//
#include <hip/hip_runtime.h>
#include <stdint.h>
#include <math.h>

#define B_ 4
#define S_ 2048
#define C_ 256
#define H_ 8

typedef short bf16x8 __attribute__((ext_vector_type(8)));
typedef float f32x4 __attribute__((ext_vector_type(4)));

static __device__ __forceinline__ short f2bf(float f) {
  uint32_t u = __float_as_uint(f);
  u = (u + 0x7fffu + ((u >> 16) & 1u)) >> 16;
  return (short)u;
}

static __device__ __forceinline__ void gld16(const void* g, void* l) {
  __builtin_amdgcn_global_load_lds(
      (const __attribute__((address_space(1))) uint32_t*)g,
      (__attribute__((address_space(3))) uint32_t*)l, 16, 0, 0);
}

// ---------------- elementwise convert fp32 -> bf16 ----------------
__global__ void cvt_f32_bf16(const float* __restrict__ in, short* __restrict__ out, int n) {
  int i = (blockIdx.x * 256 + threadIdx.x) * 8;
  if (i >= n) return;
  float4 a = *(const float4*)(in + i);
  float4 b = *(const float4*)(in + i + 4);
  bf16x8 r;
  r[0] = f2bf(a.x); r[1] = f2bf(a.y); r[2] = f2bf(a.z); r[3] = f2bf(a.w);
  r[4] = f2bf(b.x); r[5] = f2bf(b.y); r[6] = f2bf(b.z); r[7] = f2bf(b.w);
  *(bf16x8*)(out + i) = r;
}

// ---------------- transpose-convert: in fp32 (R x Cc) -> out bf16 (Cc x R) ----
__global__ void transpose_cvt(const float* __restrict__ in, short* __restrict__ out,
                              int R, int Cc) {
  __shared__ float t[32][33];
  int cb = blockIdx.x * 32, rb = blockIdx.y * 32;
  int tr = threadIdx.x >> 5;   // 0..7
  int tc = threadIdx.x & 31;
#pragma unroll
  for (int i = 0; i < 4; i++)
    t[tr + i * 8][tc] = in[(size_t)(rb + tr + i * 8) * Cc + cb + tc];
  __syncthreads();
#pragma unroll
  for (int i = 0; i < 4; i++)
    out[(size_t)(cb + tr + i * 8) * R + rb + tc] = f2bf(t[tc][tr + i * 8]);
}

// ---------------- GEMM: A (MxK bf16) * Bt^T (Bt is NxK bf16) + bias ----------
// MODE 0: out bf16 at (B,H,S,C) layout, val=(acc+bias)*scale   (Q,K proj)
// MODE 1: out bf16 at (B,H,C,S) layout (transposed via LDS)    (V proj)
// MODE 2: out fp32 at (M,N) layout, val=acc+bias               (output proj)
template<int MODE>
__global__ void __launch_bounds__(256, 2) gemm_k(
    const short* __restrict__ A, const short* __restrict__ Bt,
    const float* __restrict__ bias, float scale, void* __restrict__ out,
    int M, int N, int K) {
  __shared__ char smem[36864];
  const int tid = threadIdx.x;
  const int l = tid & 63;
  const int w = tid >> 6;
  const int wr = w >> 1, wc = w & 1;
  const int mbase = blockIdx.y * 128;
  const int nbase = blockIdx.x * 128;

  const f32x4 fzero = {0.f, 0.f, 0.f, 0.f};
  f32x4 acc[4][4];
#pragma unroll
  for (int i = 0; i < 4; i++)
#pragma unroll
    for (int j = 0; j < 4; j++) acc[i][j] = fzero;

  const int nkt = K >> 5;
  for (int kt = 0; kt < nkt; ++kt) {
    // stage A,B tiles: [128][32] bf16 each, linear LDS
#pragma unroll
    for (int c = 0; c < 2; c++) {
      int row = c * 64 + w * 16 + (l >> 2);
      const short* ga = A + (size_t)(mbase + row) * K + kt * 32 + (l & 3) * 8;
      gld16(ga, smem + (c * 4 + w) * 1024);
      const short* gb = Bt + (size_t)(nbase + row) * K + kt * 32 + (l & 3) * 8;
      gld16(gb, smem + 8192 + (c * 4 + w) * 1024);
    }
    __syncthreads();
    bf16x8 af[4], bf[4];
#pragma unroll
    for (int mf = 0; mf < 4; mf++)
      af[mf] = *(const bf16x8*)(smem + (wr * 64 + mf * 16 + (l & 15)) * 64 + ((l >> 4) << 4));
#pragma unroll
    for (int nf = 0; nf < 4; nf++)
      bf[nf] = *(const bf16x8*)(smem + 8192 + (wc * 64 + nf * 16 + (l & 15)) * 64 + ((l >> 4) << 4));
#pragma unroll
    for (int mf = 0; mf < 4; mf++)
#pragma unroll
      for (int nf = 0; nf < 4; nf++)
        acc[mf][nf] = __builtin_amdgcn_mfma_f32_16x16x32_bf16(af[mf], bf[nf], acc[mf][nf], 0, 0, 0);
    __syncthreads();
  }

  if (MODE == 0) {
#pragma unroll
    for (int mf = 0; mf < 4; mf++)
#pragma unroll
      for (int nf = 0; nf < 4; nf++)
#pragma unroll
        for (int i = 0; i < 4; i++) {
          int m = mbase + wr * 64 + mf * 16 + (l >> 4) * 4 + i;
          int n = nbase + wc * 64 + nf * 16 + (l & 15);
          float v = (acc[mf][nf][i] + bias[n]) * scale;
          int b = m >> 11, s = m & 2047;
          int h = n >> 8, d = n & 255;
          ((short*)out)[((size_t)(b * H_ + h) * S_ + s) * C_ + d] = f2bf(v);
        }
  } else if (MODE == 2) {
#pragma unroll
    for (int mf = 0; mf < 4; mf++)
#pragma unroll
      for (int nf = 0; nf < 4; nf++)
#pragma unroll
        for (int i = 0; i < 4; i++) {
          int m = mbase + wr * 64 + mf * 16 + (l >> 4) * 4 + i;
          int n = nbase + wc * 64 + nf * 16 + (l & 15);
          ((float*)out)[(size_t)m * N + n] = acc[mf][nf][i] + bias[n];
        }
  } else {
    // V: transpose 128x128 tile through LDS, write (B,H,C,S) coalesced
    short* T = (short*)smem;  // [128][136]
#pragma unroll
    for (int mf = 0; mf < 4; mf++)
#pragma unroll
      for (int nf = 0; nf < 4; nf++)
#pragma unroll
        for (int i = 0; i < 4; i++) {
          int ml = wr * 64 + mf * 16 + (l >> 4) * 4 + i;
          int nl = wc * 64 + nf * 16 + (l & 15);
          float v = acc[mf][nf][i] + bias[nbase + nl];
          T[ml * 136 + nl] = f2bf(v);
        }
    __syncthreads();
    int b = mbase >> 11, s0 = mbase & 2047;
    int h = nbase >> 8, d0 = nbase & 255;
#pragma unroll
    for (int r = 0; r < 8; r++) {
      int dl = r * 16 + (tid >> 4);
      int sc = (tid & 15) * 8;
      bf16x8 pack;
#pragma unroll
      for (int j = 0; j < 8; j++) pack[j] = T[(sc + j) * 136 + dl];
      *(bf16x8*)((short*)out + ((size_t)(b * H_ + h) * C_ + d0 + dl) * S_ + s0 + sc) = pack;
    }
  }
}

// ---------------- flash attention -------------------------------------------
// grid: (S/64, B*H). block 256 = 4 waves; wave owns 16 q-rows.
// Qg,Kg: (B,H,S,C) bf16 (pre-scaled). Vtg: (B,H,C,S) bf16. Ag out: (B,S,H*C) bf16.
__global__ void __launch_bounds__(256, 2) attn_k(
    const short* __restrict__ Qg, const short* __restrict__ Kg,
    const short* __restrict__ Vtg, short* __restrict__ Ag) {
  __shared__ char smem[73728];
  char* Ks = smem;            // [64][256] bf16, XOR-swizzled rows (512B)
  char* Vs = smem + 32768;    // [256][64] bf16, XOR-swizzled rows (128B)
  char* Ps = smem + 65536;    // 4 x [16][64] bf16, XOR-swizzled rows (128B)
  const int tid = threadIdx.x, l = tid & 63, w = tid >> 6;
  const int head = blockIdx.y;               // b*H + h
  const int qrow0 = blockIdx.x * 64 + w * 16;

  // Q fragments in registers: rows qrow0+(l&15), 8 k-steps of 32 over D=256
  bf16x8 q[8];
  const short* qb = Qg + ((size_t)head * S_ + qrow0 + (l & 15)) * C_;
#pragma unroll
  for (int ks = 0; ks < 8; ks++)
    q[ks] = *(const bf16x8*)(qb + ks * 32 + ((l >> 4) << 3));

  const f32x4 fzero = {0.f, 0.f, 0.f, 0.f};
  f32x4 o[16];
#pragma unroll
  for (int i = 0; i < 16; i++) o[i] = fzero;
  float mrun[4], lrun[4];
#pragma unroll
  for (int i = 0; i < 4; i++) { mrun[i] = -__builtin_inff(); lrun[i] = 0.f; }

  const size_t kgbase = (size_t)head * S_ * C_;
  const size_t vgbase = (size_t)head * C_ * S_;
  char* pw = Ps + w * 2048;

  for (int kt = 0; kt < 32; ++kt) {
    // ---- stage K tile [64][256] and Vt tile [256][64], swizzled global src
#pragma unroll
    for (int c = 0; c < 8; c++) {
      int seg = c * 4 + w;
      int rk = seg * 2 + (l >> 5);
      const char* gk = (const char*)Kg + ((kgbase + (size_t)(kt * 64 + rk) * C_) << 1)
                     + (((l & 31) * 16) ^ ((rk & 7) << 4));
      gld16(gk, Ks + seg * 1024);
      int rv = seg * 8 + (l >> 3);
      const char* gv = (const char*)Vtg + ((vgbase + (size_t)rv * S_ + (size_t)kt * 64) << 1)
                     + (((l & 7) * 16) ^ ((rv & 7) << 4));
      gld16(gv, Vs + seg * 1024);
    }
    __syncthreads();

    // ---- S = Q K^T (16 x 64 per wave)
    f32x4 sa[4];
#pragma unroll
    for (int nf = 0; nf < 4; nf++) sa[nf] = fzero;
#pragma unroll
    for (int ks = 0; ks < 8; ks++) {
#pragma unroll
      for (int nf = 0; nf < 4; nf++) {
        int row = nf * 16 + (l & 15);
        bf16x8 kb = *(const bf16x8*)(Ks + row * 512 +
                       ((ks * 64 + ((l >> 4) << 4)) ^ ((row & 7) << 4)));
        sa[nf] = __builtin_amdgcn_mfma_f32_16x16x32_bf16(q[ks], kb, sa[nf], 0, 0, 0);
      }
    }

    // ---- online softmax (rows: (l>>4)*4+i, cols: nf*16+(l&15))
#pragma unroll
    for (int i = 0; i < 4; i++) {
      float pm = fmaxf(fmaxf(sa[0][i], sa[1][i]), fmaxf(sa[2][i], sa[3][i]));
      pm = fmaxf(pm, __shfl_xor(pm, 1));
      pm = fmaxf(pm, __shfl_xor(pm, 2));
      pm = fmaxf(pm, __shfl_xor(pm, 4));
      pm = fmaxf(pm, __shfl_xor(pm, 8));
      float mn = fmaxf(mrun[i], pm);
      float al = exp2f((mrun[i] - mn) * 1.44269504088896f);
      mrun[i] = mn;
      float rs = 0.f;
#pragma unroll
      for (int nf = 0; nf < 4; nf++) {
        float p = exp2f((sa[nf][i] - mn) * 1.44269504088896f);
        sa[nf][i] = p;
        rs += p;
      }
      rs += __shfl_xor(rs, 1); rs += __shfl_xor(rs, 2);
      rs += __shfl_xor(rs, 4); rs += __shfl_xor(rs, 8);
      lrun[i] = lrun[i] * al + rs;
#pragma unroll
      for (int nf = 0; nf < 16; nf++) o[nf][i] *= al;
    }

    // ---- P (C-layout) -> LDS bf16 (swizzled), reread as A-fragments
#pragma unroll
    for (int nf = 0; nf < 4; nf++)
#pragma unroll
      for (int i = 0; i < 4; i++) {
        int row = (l >> 4) * 4 + i;
        int colb = (nf * 16 + (l & 15)) * 2;
        *(short*)(pw + row * 128 + (colb ^ ((row & 7) << 4))) = f2bf(sa[nf][i]);
      }

    // ---- O += P * V  (contraction over 64 keys = 2 mfma K-steps)
#pragma unroll
    for (int kb = 0; kb < 2; kb++) {
      int prow = l & 15;
      bf16x8 pa = *(const bf16x8*)(pw + prow * 128 +
                     ((kb * 64 + ((l >> 4) << 4)) ^ ((prow & 7) << 4)));
#pragma unroll
      for (int nf = 0; nf < 16; nf++) {
        int vrow = nf * 16 + (l & 15);
        bf16x8 vb = *(const bf16x8*)(Vs + vrow * 128 +
                       ((kb * 64 + ((l >> 4) << 4)) ^ ((vrow & 7) << 4)));
        o[nf] = __builtin_amdgcn_mfma_f32_16x16x32_bf16(pa, vb, o[nf], 0, 0, 0);
      }
    }
    __syncthreads();
  }

  // ---- epilogue: normalize, write (B,S,H*C) bf16
  int b = head >> 3, h = head & 7;
#pragma unroll
  for (int i = 0; i < 4; i++) {
    float inv = 1.0f / lrun[i];
    int s = qrow0 + (l >> 4) * 4 + i;
    size_t rb = ((size_t)b * S_ + s) * (H_ * C_) + h * C_;
#pragma unroll
    for (int nf = 0; nf < 16; nf++)
      Ag[rb + nf * 16 + (l & 15)] = f2bf(o[nf][i] * inv);
  }
}

// ---------------- launch ----------------------------------------------------
extern "C" void kernel_launch(void* const* d_in, const int* in_sizes, int n_in,
                              void* d_out, int out_size, void* d_ws, size_t ws_size,
                              hipStream_t stream) {
  const float* x  = (const float*)d_in[0];
  const float* Wq = (const float*)d_in[1];
  const float* bq = (const float*)d_in[2];
  const float* Wk = (const float*)d_in[3];
  const float* bk = (const float*)d_in[4];
  const float* Wv = (const float*)d_in[5];
  const float* bv = (const float*)d_in[6];
  const float* Wo = (const float*)d_in[7];
  const float* bo = (const float*)d_in[8];

  char* ws = (char*)d_ws;
  short* xb  = (short*)(ws);               //  4 MB  (8192x256 bf16)
  short* WqT = (short*)(ws + 4194304);     //  1 MB  (2048x256 bf16)
  short* WkT = (short*)(ws + 5242880);
  short* WvT = (short*)(ws + 6291456);
  short* WoT = (short*)(ws + 7340032);     //  1 MB  (256x2048 bf16)
  short* Qg  = (short*)(ws + 8388608);     // 32 MB  (B,H,S,C)
  short* Kg  = (short*)(ws + 41943040);    // 32 MB
  short* Vt  = (short*)(ws + 75497472);    // 32 MB  (B,H,C,S)
  short* Ag  = (short*)(ws + 109051904);   // 32 MB  (B,S,H*C)

  cvt_f32_bf16<<<1024, 256, 0, stream>>>(x, xb, 8192 * 256);
  transpose_cvt<<<dim3(64, 8), 256, 0, stream>>>(Wq, WqT, 256, 2048);
  transpose_cvt<<<dim3(64, 8), 256, 0, stream>>>(Wk, WkT, 256, 2048);
  transpose_cvt<<<dim3(64, 8), 256, 0, stream>>>(Wv, WvT, 256, 2048);
  transpose_cvt<<<dim3(8, 64), 256, 0, stream>>>(Wo, WoT, 2048, 256);

  const float sc = 0.25f;  // 256^(-1/4)
  gemm_k<0><<<dim3(16, 64), 256, 0, stream>>>(xb, WqT, bq, sc, Qg, 8192, 2048, 256);
  gemm_k<0><<<dim3(16, 64), 256, 0, stream>>>(xb, WkT, bk, sc, Kg, 8192, 2048, 256);
  gemm_k<1><<<dim3(16, 64), 256, 0, stream>>>(xb, WvT, bv, 1.0f, Vt, 8192, 2048, 256);
  attn_k<<<dim3(32, 32), 256, 0, stream>>>(Qg, Kg, Vt, Ag);
  gemm_k<2><<<dim3(2, 64), 256, 0, stream>>>(Ag, WoT, bo, 1.0f, (float*)d_out, 8192, 256, 2048);
}